// Round 1
// baseline (1471.351 us; speedup 1.0000x reference)
//
#include <hip/hip_runtime.h>

#define Nn 20000
#define Ee 320000
#define Hh 4
#define Cc 128
#define HC 512
#define Gg 1024
#define NFt 9
#define EFt 4
#define GFt 50
#define EPSf 1e-5f
#define SLOPE 0.2f

__device__ __forceinline__ unsigned encf(float f) {
    unsigned b = __float_as_uint(f);
    return (b & 0x80000000u) ? ~b : (b | 0x80000000u);
}
__device__ __forceinline__ float decf(unsigned u) {
    unsigned b = (u & 0x80000000u) ? (u ^ 0x80000000u) : ~u;
    return __uint_as_float(b);
}

// ---------- degree + edge_attr segment sum (for self-loop mean fill) ----------
__global__ void k_deg(const int* __restrict__ dst, const float* __restrict__ ea,
                      int* __restrict__ deg, float* __restrict__ easum) {
    int e = blockIdx.x * 256 + threadIdx.x;
    if (e >= Ee) return;
    int d = dst[e];
    atomicAdd(&deg[d], 1);
    float4 v = ((const float4*)ea)[e];
    atomicAdd(&easum[d * 4 + 0], v.x);
    atomicAdd(&easum[d * 4 + 1], v.y);
    atomicAdd(&easum[d * 4 + 2], v.z);
    atomicAdd(&easum[d * 4 + 3], v.w);
}

// ---------- one-block exclusive scan of deg -> rowptr ----------
__global__ void k_scan(const int* __restrict__ deg, int* __restrict__ rowptr) {
    __shared__ int sums[1024];
    int t = threadIdx.x;
    const int n = Nn;
    int chunk = (n + 1023) / 1024;
    int start = t * chunk;
    int lim = min(start + chunk, n);
    int s = 0;
    for (int i = start; i < lim; ++i) s += deg[i];
    sums[t] = s;
    __syncthreads();
    for (int off = 1; off < 1024; off <<= 1) {
        int v = (t >= off) ? sums[t - off] : 0;
        __syncthreads();
        sums[t] += v;
        __syncthreads();
    }
    int run = (t == 0) ? 0 : sums[t - 1];
    for (int i = start; i < lim; ++i) { rowptr[i] = run; run += deg[i]; }
    if (t == 1023) rowptr[n] = sums[1023];
}

// ---------- counting-sort scatter: csr[pos] = edge id (grouped by dst) ----------
__global__ void k_scatter(const int* __restrict__ dst, const int* __restrict__ rowptr,
                          int* __restrict__ fill, int* __restrict__ csr) {
    int e = blockIdx.x * 256 + threadIdx.x;
    if (e >= Ee) return;
    int d = dst[e];
    int pos = rowptr[d] + atomicAdd(&fill[d], 1);
    csr[pos] = e;
}

// ---------- layer-1 node transforms (K=9) ----------
__global__ void k_xlxr1(const float* __restrict__ x, const float* __restrict__ Wl,
                        const float* __restrict__ Wr, float* __restrict__ xl,
                        float* __restrict__ xr) {
    int idx = blockIdx.x * 256 + threadIdx.x;
    if (idx >= Nn * HC) return;
    int n = idx >> 9, c = idx & 511;
    float al = 0.f, arr = 0.f;
#pragma unroll
    for (int f = 0; f < NFt; ++f) {
        float xv = x[n * NFt + f];
        al += xv * Wl[f * HC + c];
        arr += xv * Wr[f * HC + c];
    }
    xl[idx] = al;
    xr[idx] = arr;
}

// ---------- fp32 tiled GEMM: C[M x 512] = A[M x 512] @ B[512 x 512] ----------
__global__ __launch_bounds__(256) void k_gemm64(const float* __restrict__ A,
                                                const float* __restrict__ B,
                                                float* __restrict__ Cm, int M) {
    const int K = 512, NN = 512;
    __shared__ float As[16][65];
    __shared__ float Bs[16][65];
    int tx = threadIdx.x & 15;
    int ty = threadIdx.x >> 4;
    int bm = blockIdx.x * 64;
    int bn = blockIdx.y * 64;
    float acc[4][4] = {};
    for (int k0 = 0; k0 < K; k0 += 16) {
        int kk = threadIdx.x & 15, r = threadIdx.x >> 4;
#pragma unroll
        for (int i = 0; i < 4; i++) {
            int row = bm + r + i * 16;
            As[kk][r + i * 16] = (row < M) ? A[(size_t)row * K + k0 + kk] : 0.f;
        }
        int nn = threadIdx.x & 63, kr = threadIdx.x >> 6;
#pragma unroll
        for (int i = 0; i < 4; i++) {
            Bs[kr + i * 4][nn] = B[(size_t)(k0 + kr + i * 4) * NN + bn + nn];
        }
        __syncthreads();
#pragma unroll
        for (int kk2 = 0; kk2 < 16; kk2++) {
            float a[4], b[4];
#pragma unroll
            for (int i = 0; i < 4; i++) a[i] = As[kk2][ty * 4 + i];
#pragma unroll
            for (int j = 0; j < 4; j++) b[j] = Bs[kk2][tx * 4 + j];
#pragma unroll
            for (int i = 0; i < 4; i++)
#pragma unroll
                for (int j = 0; j < 4; j++) acc[i][j] += a[i] * b[j];
        }
        __syncthreads();
    }
#pragma unroll
    for (int i = 0; i < 4; i++) {
        int row = bm + ty * 4 + i;
        if (row >= M) continue;
#pragma unroll
        for (int j = 0; j < 4; j++) {
            Cm[(size_t)row * NN + bn + tx * 4 + j] = acc[i][j];
        }
    }
}

// ---------- per-(edge|self-loop) logits + segment max ----------
__global__ __launch_bounds__(256) void k_logits(
    const float* __restrict__ xl, const float* __restrict__ xr,
    const float* __restrict__ We, const float* __restrict__ att,
    const int* __restrict__ src, const int* __restrict__ dstA,
    const float* __restrict__ ea, const float* __restrict__ easum,
    const int* __restrict__ deg, float* __restrict__ logits,
    unsigned* __restrict__ mseg) {
    int lane = threadIdx.x & 63;
    int wave = (blockIdx.x * 256 + threadIdx.x) >> 6;
    int nwaves = (gridDim.x * 256) >> 6;
    int ch0 = lane * 8;
    int head = lane >> 4;
    float wr[4][8], ar[8];
#pragma unroll
    for (int f = 0; f < 4; ++f)
#pragma unroll
        for (int k = 0; k < 8; ++k) wr[f][k] = We[f * HC + ch0 + k];
#pragma unroll
    for (int k = 0; k < 8; ++k) ar[k] = att[ch0 + k];

    for (int idx = wave; idx < Ee + Nn; idx += nwaves) {
        int s, d;
        float eaf[4];
        if (idx < Ee) {
            s = src[idx];
            d = dstA[idx];
            float4 v = ((const float4*)ea)[idx];
            eaf[0] = v.x; eaf[1] = v.y; eaf[2] = v.z; eaf[3] = v.w;
        } else {
            int n = idx - Ee;
            s = n; d = n;
            float dv = (float)max(deg[n], 1);
            float4 v = ((const float4*)easum)[n];
            eaf[0] = v.x / dv; eaf[1] = v.y / dv; eaf[2] = v.z / dv; eaf[3] = v.w / dv;
        }
        const float4* pl = (const float4*)(xl + (size_t)s * HC + ch0);
        const float4* pr = (const float4*)(xr + (size_t)d * HC + ch0);
        float4 l0 = pl[0], l1 = pl[1];
        float4 r0 = pr[0], r1 = pr[1];
        float xa[8] = {l0.x, l0.y, l0.z, l0.w, l1.x, l1.y, l1.z, l1.w};
        float xb[8] = {r0.x, r0.y, r0.z, r0.w, r1.x, r1.y, r1.z, r1.w};
        float p = 0.f;
#pragma unroll
        for (int k = 0; k < 8; ++k) {
            float v = xa[k] + xb[k] + eaf[0] * wr[0][k] + eaf[1] * wr[1][k] +
                      eaf[2] * wr[2][k] + eaf[3] * wr[3][k];
            v = (v > 0.f) ? v : SLOPE * v;
            p += v * ar[k];
        }
#pragma unroll
        for (int off = 8; off; off >>= 1) p += __shfl_xor(p, off);
        if ((lane & 15) == 0) {
            logits[(size_t)idx * 4 + head] = p;
            atomicMax(&mseg[d * 4 + head], encf(p));
        }
    }
}

// ---------- exp(logit - segmax) and segment denom ----------
__global__ void k_expdenom(const int* __restrict__ dstA, float* __restrict__ logits,
                           const unsigned* __restrict__ mseg, float* __restrict__ denom) {
    int idx = blockIdx.x * 256 + threadIdx.x;
    if (idx >= Ee + Nn) return;
    int d = (idx < Ee) ? dstA[idx] : (idx - Ee);
    float4 lg = ((const float4*)logits)[idx];
    float e0 = expf(lg.x - decf(mseg[d * 4 + 0]));
    float e1 = expf(lg.y - decf(mseg[d * 4 + 1]));
    float e2 = expf(lg.z - decf(mseg[d * 4 + 2]));
    float e3 = expf(lg.w - decf(mseg[d * 4 + 3]));
    ((float4*)logits)[idx] = make_float4(e0, e1, e2, e3);
    atomicAdd(&denom[d * 4 + 0], e0);
    atomicAdd(&denom[d * 4 + 1], e1);
    atomicAdd(&denom[d * 4 + 2], e2);
    atomicAdd(&denom[d * 4 + 3], e3);
}

// ---------- per-node gather aggregate + bias + BN + ReLU ----------
__global__ __launch_bounds__(256) void k_aggregate(
    const float* __restrict__ xl, const float* __restrict__ logits,
    const float* __restrict__ denom, const int* __restrict__ rowptr,
    const int* __restrict__ csr, const int* __restrict__ src,
    const float* __restrict__ bias, const float* __restrict__ gamma,
    const float* __restrict__ beta, const float* __restrict__ mean,
    const float* __restrict__ var, float* __restrict__ hout) {
    __shared__ int s_src[64];
    __shared__ float s_ex[64][4];
    int n = blockIdx.x;
    int t = threadIdx.x;
    int c0 = t, c1 = t + 256;
    int h0 = c0 >> 7, h1 = h0 + 2;
    float inv0 = 1.f / denom[n * 4 + h0];
    float inv1 = 1.f / denom[n * 4 + h1];
    float acc0 = 0.f, acc1 = 0.f;
    int start = rowptr[n], end = rowptr[n + 1];
    for (int j0 = start; j0 < end; j0 += 64) {
        int m = min(64, end - j0);
        __syncthreads();
        if (t < m) {
            int eid = csr[j0 + t];
            s_src[t] = src[eid];
            float4 exv = ((const float4*)logits)[eid];
            s_ex[t][0] = exv.x; s_ex[t][1] = exv.y; s_ex[t][2] = exv.z; s_ex[t][3] = exv.w;
        }
        __syncthreads();
        for (int i = 0; i < m; ++i) {
            int s = s_src[i];
            acc0 += s_ex[i][h0] * inv0 * xl[(size_t)s * HC + c0];
            acc1 += s_ex[i][h1] * inv1 * xl[(size_t)s * HC + c1];
        }
    }
    {
        float4 exv = ((const float4*)logits)[Ee + n];
        float seh0 = (h0 == 0) ? exv.x : exv.y;
        float seh1 = (h0 == 0) ? exv.z : exv.w;
        acc0 += seh0 * inv0 * xl[(size_t)n * HC + c0];
        acc1 += seh1 * inv1 * xl[(size_t)n * HC + c1];
    }
    float v0 = acc0 + bias[c0];
    v0 = (v0 - mean[c0]) * rsqrtf(var[c0] + EPSf) * gamma[c0] + beta[c0];
    hout[(size_t)n * HC + c0] = fmaxf(v0, 0.f);
    float v1 = acc1 + bias[c1];
    v1 = (v1 - mean[c1]) * rsqrtf(var[c1] + EPSf) * gamma[c1] + beta[c1];
    hout[(size_t)n * HC + c1] = fmaxf(v1, 0.f);
}

// ---------- graph size counts ----------
__global__ void k_cnt(const int* __restrict__ batch, float* __restrict__ cnt) {
    int i = blockIdx.x * 256 + threadIdx.x;
    if (i < Nn) atomicAdd(&cnt[batch[i]], 1.f);
}

// ---------- mean-pool accumulate ----------
__global__ void k_pool(const float* __restrict__ h, const int* __restrict__ batch,
                       float* __restrict__ pooled) {
    int idx = blockIdx.x * 256 + threadIdx.x;
    if (idx >= Nn * HC) return;
    int n = idx >> 9, c = idx & 511;
    atomicAdd(&pooled[(size_t)batch[n] * HC + c], h[idx]);
}

// ---------- final MLP: relu([pooled/cnt, gfeat] @ fc1 + b1) @ fc2 + b2 ----------
__global__ __launch_bounds__(128) void k_mlp(const float* __restrict__ pooled,
                                             const float* __restrict__ cnt,
                                             const float* __restrict__ gfeat,
                                             const float* __restrict__ fc1w,
                                             const float* __restrict__ fc1b,
                                             const float* __restrict__ fc2w,
                                             const float* __restrict__ fc2b,
                                             float* __restrict__ out) {
    __shared__ float z[HC + GFt];
    __shared__ float red[128];
    int g = blockIdx.x, t = threadIdx.x;
    float ic = 1.f / fmaxf(cnt[g], 1.f);
    for (int i = t; i < HC; i += 128) z[i] = pooled[(size_t)g * HC + i] * ic;
    for (int i = HC + t; i < HC + GFt; i += 128) z[i] = gfeat[g * GFt + (i - HC)];
    __syncthreads();
    float acc = fc1b[t];
    for (int j = 0; j < HC + GFt; ++j) acc += z[j] * fc1w[j * 128 + t];
    float r = fmaxf(acc, 0.f) * fc2w[t];
    red[t] = r;
    __syncthreads();
    for (int off = 64; off; off >>= 1) {
        if (t < off) red[t] += red[t + off];
        __syncthreads();
    }
    if (t == 0) out[g] = red[0] + fc2b[0];
}

extern "C" void kernel_launch(void* const* d_in, const int* in_sizes, int n_in,
                              void* d_out, int out_size, void* d_ws, size_t ws_size,
                              hipStream_t stream) {
    const float* x = (const float*)d_in[0];
    const float* ea = (const float*)d_in[1];
    const float* gfeat = (const float*)d_in[2];
    const float* Wl1 = (const float*)d_in[3];
    const float* Wr1 = (const float*)d_in[4];
    const float* We1 = (const float*)d_in[5];
    const float* att1 = (const float*)d_in[6];
    const float* b1 = (const float*)d_in[7];
    const float* gamma1 = (const float*)d_in[8];
    const float* beta1 = (const float*)d_in[9];
    const float* mean1 = (const float*)d_in[10];
    const float* var1 = (const float*)d_in[11];
    const float* Wl2 = (const float*)d_in[12];
    const float* Wr2 = (const float*)d_in[13];
    const float* We2 = (const float*)d_in[14];
    const float* att2 = (const float*)d_in[15];
    const float* b2 = (const float*)d_in[16];
    const float* gamma2 = (const float*)d_in[17];
    const float* beta2 = (const float*)d_in[18];
    const float* mean2 = (const float*)d_in[19];
    const float* var2 = (const float*)d_in[20];
    const float* fc1w = (const float*)d_in[21];
    const float* fc1b = (const float*)d_in[22];
    const float* fc2w = (const float*)d_in[23];
    const float* fc2b = (const float*)d_in[24];
    const int* eidx = (const int*)d_in[25];
    const int* batch = (const int*)d_in[26];
    float* out = (float*)d_out;

    const int* srcp = eidx;
    const int* dstp = eidx + Ee;

    char* p = (char*)d_ws;
    auto alloc = [&](size_t bytes) -> char* {
        char* r = p;
        p += (bytes + 255) & ~(size_t)255;
        return r;
    };
    float* xl = (float*)alloc((size_t)Nn * HC * 4);
    float* xr = (float*)alloc((size_t)Nn * HC * 4);
    float* h = (float*)alloc((size_t)Nn * HC * 4);
    float* logits = (float*)alloc((size_t)(Ee + Nn) * 4 * 4);
    float* denom = (float*)alloc((size_t)Nn * 4 * 4);
    unsigned* mseg = (unsigned*)alloc((size_t)Nn * 4 * 4);
    float* easum = (float*)alloc((size_t)Nn * 4 * 4);
    int* deg = (int*)alloc((size_t)Nn * 4);
    int* fill = (int*)alloc((size_t)Nn * 4);
    int* rowptr = (int*)alloc((size_t)(Nn + 1) * 4);
    int* csr = (int*)alloc((size_t)Ee * 4);
    float* pooled = (float*)alloc((size_t)Gg * HC * 4);
    float* cnt = (float*)alloc((size_t)Gg * 4);

    hipMemsetAsync(deg, 0, (size_t)Nn * 4, stream);
    hipMemsetAsync(fill, 0, (size_t)Nn * 4, stream);
    hipMemsetAsync(easum, 0, (size_t)Nn * 4 * 4, stream);
    hipMemsetAsync(mseg, 0, (size_t)Nn * 4 * 4, stream);
    hipMemsetAsync(denom, 0, (size_t)Nn * 4 * 4, stream);
    hipMemsetAsync(pooled, 0, (size_t)Gg * HC * 4, stream);
    hipMemsetAsync(cnt, 0, (size_t)Gg * 4, stream);

    k_deg<<<(Ee + 255) / 256, 256, 0, stream>>>(dstp, ea, deg, easum);
    k_scan<<<1, 1024, 0, stream>>>(deg, rowptr);
    k_scatter<<<(Ee + 255) / 256, 256, 0, stream>>>(dstp, rowptr, fill, csr);

    // ----- layer 1 -----
    k_xlxr1<<<(Nn * HC + 255) / 256, 256, 0, stream>>>(x, Wl1, Wr1, xl, xr);
    k_logits<<<4096, 256, 0, stream>>>(xl, xr, We1, att1, srcp, dstp, ea, easum, deg,
                                       logits, mseg);
    k_expdenom<<<(Ee + Nn + 255) / 256, 256, 0, stream>>>(dstp, logits, mseg, denom);
    k_aggregate<<<Nn, 256, 0, stream>>>(xl, logits, denom, rowptr, csr, srcp, b1,
                                        gamma1, beta1, mean1, var1, h);

    // ----- layer 2 -----
    hipMemsetAsync(mseg, 0, (size_t)Nn * 4 * 4, stream);
    hipMemsetAsync(denom, 0, (size_t)Nn * 4 * 4, stream);
    k_gemm64<<<dim3((Nn + 63) / 64, 8), 256, 0, stream>>>(h, Wl2, xl, Nn);
    k_gemm64<<<dim3((Nn + 63) / 64, 8), 256, 0, stream>>>(h, Wr2, xr, Nn);
    k_logits<<<4096, 256, 0, stream>>>(xl, xr, We2, att2, srcp, dstp, ea, easum, deg,
                                       logits, mseg);
    k_expdenom<<<(Ee + Nn + 255) / 256, 256, 0, stream>>>(dstp, logits, mseg, denom);
    k_aggregate<<<Nn, 256, 0, stream>>>(xl, logits, denom, rowptr, csr, srcp, b2,
                                        gamma2, beta2, mean2, var2, h);

    // ----- pooling + MLP -----
    k_cnt<<<(Nn + 255) / 256, 256, 0, stream>>>(batch, cnt);
    k_pool<<<(Nn * HC + 255) / 256, 256, 0, stream>>>(h, batch, pooled);
    k_mlp<<<Gg, 128, 0, stream>>>(pooled, cnt, gfeat, fc1w, fc1b, fc2w, fc2b, out);
}

// Round 2
// 1065.666 us; speedup vs baseline: 1.3807x; 1.3807x over previous
//
#include <hip/hip_runtime.h>
#include <hip/hip_bf16.h>

#define Nn 20000
#define Ee 320000
#define Hh 4
#define Cc 128
#define HC 512
#define Gg 1024
#define NFt 9
#define EFt 4
#define GFt 50
#define EPSf 1e-5f
#define SLOPE 0.2f

typedef __attribute__((ext_vector_type(8))) short bf16x8;
typedef __attribute__((ext_vector_type(4))) float f32x4;

__device__ __forceinline__ unsigned encf(float f) {
    unsigned b = __float_as_uint(f);
    return (b & 0x80000000u) ? ~b : (b | 0x80000000u);
}
__device__ __forceinline__ float decf(unsigned u) {
    unsigned b = (u & 0x80000000u) ? (u ^ 0x80000000u) : ~u;
    return __uint_as_float(b);
}

typedef const __attribute__((address_space(1))) unsigned char* gp1_t;
typedef __attribute__((address_space(3))) unsigned char* lp3_t;
__device__ __forceinline__ void gload16(const void* g, void* l) {
    __builtin_amdgcn_global_load_lds((gp1_t)g, (lp3_t)l, 16, 0, 0);
}

// ---------- degree + edge_attr segment sum (for self-loop mean fill) ----------
__global__ void k_deg(const int* __restrict__ dst, const float* __restrict__ ea,
                      int* __restrict__ deg, float* __restrict__ easum) {
    int e = blockIdx.x * 256 + threadIdx.x;
    if (e >= Ee) return;
    int d = dst[e];
    atomicAdd(&deg[d], 1);
    float4 v = ((const float4*)ea)[e];
    atomicAdd(&easum[d * 4 + 0], v.x);
    atomicAdd(&easum[d * 4 + 1], v.y);
    atomicAdd(&easum[d * 4 + 2], v.z);
    atomicAdd(&easum[d * 4 + 3], v.w);
}

// ---------- one-block exclusive scan of deg -> rowptr ----------
__global__ void k_scan(const int* __restrict__ deg, int* __restrict__ rowptr) {
    __shared__ int sums[1024];
    int t = threadIdx.x;
    const int n = Nn;
    int chunk = (n + 1023) / 1024;
    int start = t * chunk;
    int lim = min(start + chunk, n);
    int s = 0;
    for (int i = start; i < lim; ++i) s += deg[i];
    sums[t] = s;
    __syncthreads();
    for (int off = 1; off < 1024; off <<= 1) {
        int v = (t >= off) ? sums[t - off] : 0;
        __syncthreads();
        sums[t] += v;
        __syncthreads();
    }
    int run = (t == 0) ? 0 : sums[t - 1];
    for (int i = start; i < lim; ++i) { rowptr[i] = run; run += deg[i]; }
    if (t == 1023) rowptr[n] = sums[1023];
}

// ---------- counting-sort scatter: csr[pos] = edge id (grouped by dst) ----------
__global__ void k_scatter(const int* __restrict__ dst, const int* __restrict__ rowptr,
                          int* __restrict__ fill, int* __restrict__ csr) {
    int e = blockIdx.x * 256 + threadIdx.x;
    if (e >= Ee) return;
    int d = dst[e];
    int pos = rowptr[d] + atomicAdd(&fill[d], 1);
    csr[pos] = e;
}

// ---------- layer-1 node transforms (K=9) ----------
__global__ void k_xlxr1(const float* __restrict__ x, const float* __restrict__ Wl,
                        const float* __restrict__ Wr, float* __restrict__ xl,
                        float* __restrict__ xr) {
    int idx = blockIdx.x * 256 + threadIdx.x;
    if (idx >= Nn * HC) return;
    int n = idx >> 9, c = idx & 511;
    float al = 0.f, arr = 0.f;
#pragma unroll
    for (int f = 0; f < NFt; ++f) {
        float xv = x[n * NFt + f];
        al += xv * Wl[f * HC + c];
        arr += xv * Wr[f * HC + c];
    }
    xl[idx] = al;
    xr[idx] = arr;
}

// ---------- convert [Wl2|Wr2] -> transposed bf16 Wt[1024][512] ----------
__global__ void k_cvtW(const float* __restrict__ Wl2, const float* __restrict__ Wr2,
                       __hip_bfloat16* __restrict__ Wt) {
    int idx = blockIdx.x * 256 + threadIdx.x;
    if (idx >= 1024 * 512) return;
    int col = idx >> 9, k = idx & 511;
    float v = (col < 512) ? Wl2[k * 512 + col] : Wr2[k * 512 + (col - 512)];
    Wt[idx] = __float2bfloat16(v);
}

// ---------- fused bf16 MFMA GEMM: [xl|xr][M x 1024] = h[M x 512] @ Wt^T ----------
// A: bf16 row-major [M][512]; B: Wt bf16 [1024 cols][512 k] (pre-transposed).
__global__ __launch_bounds__(256) void k_gemm_mfma(const short* __restrict__ Abf,
                                                   const short* __restrict__ Bt,
                                                   float* __restrict__ xl,
                                                   float* __restrict__ xr, int M) {
    __shared__ short As[128 * 32];
    __shared__ short Bs[128 * 32];
    int tid = threadIdx.x;
    int l = tid & 63;
    int wid = tid >> 6;
    int bm0 = blockIdx.x * 128;
    int bn0 = blockIdx.y * 128;
    int wr = (wid >> 1) * 64;
    int wc = (wid & 1) * 64;
    f32x4 acc[4][4] = {};

    // staging: chunk c covers rows c*16..c*16+15 of the tile; lane l handles
    // row c*16 + (l>>2), 16B granule (l&3). Granule XOR-swizzle g^=(row>>1)&3
    // applied on the SOURCE k-offset (LDS dest stays linear), and the same
    // XOR on the ds_read side -> 2-way banking (free) instead of 8-way.
    int srow = l >> 2;
    int skoff = ((l & 3) ^ ((l >> 3) & 3)) * 8;  // swizzled source granule
    int rk = (((l >> 4) ^ (l >> 1)) & 3) * 8;    // swizzled read granule

    for (int k0 = 0; k0 < 512; k0 += 32) {
        {
            int c = wid;
            long row = min(bm0 + c * 16 + srow, M - 1);
            gload16(Abf + row * 512 + k0 + skoff, &As[c * 512]);
            int col = bn0 + c * 16 + srow;
            gload16(Bt + (size_t)col * 512 + k0 + skoff, &Bs[c * 512]);
            c = wid + 4;
            row = min(bm0 + c * 16 + srow, M - 1);
            gload16(Abf + row * 512 + k0 + skoff, &As[c * 512]);
            col = bn0 + c * 16 + srow;
            gload16(Bt + (size_t)col * 512 + k0 + skoff, &Bs[c * 512]);
        }
        asm volatile("s_waitcnt vmcnt(0)" ::: "memory");
        __syncthreads();
        bf16x8 af[4], bfr[4];
#pragma unroll
        for (int m = 0; m < 4; ++m)
            af[m] = *(const bf16x8*)&As[(wr + m * 16 + (l & 15)) * 32 + rk];
#pragma unroll
        for (int n = 0; n < 4; ++n)
            bfr[n] = *(const bf16x8*)&Bs[(wc + n * 16 + (l & 15)) * 32 + rk];
#pragma unroll
        for (int m = 0; m < 4; ++m)
#pragma unroll
            for (int n = 0; n < 4; ++n)
                acc[m][n] = __builtin_amdgcn_mfma_f32_16x16x32_bf16(af[m], bfr[n],
                                                                    acc[m][n], 0, 0, 0);
        __syncthreads();
    }
    float* dst = (bn0 < 512) ? xl : xr;
    int cb = bn0 & 511;
#pragma unroll
    for (int m = 0; m < 4; ++m) {
#pragma unroll
        for (int n = 0; n < 4; ++n) {
            int col = cb + wc + n * 16 + (l & 15);
#pragma unroll
            for (int r = 0; r < 4; ++r) {
                int row = bm0 + wr + m * 16 + (l >> 4) * 4 + r;
                if (row < M) dst[(size_t)row * 512 + col] = acc[m][n][r];
            }
        }
    }
}

// ---------- per-(edge|self-loop) logits + segment max ----------
__global__ __launch_bounds__(256) void k_logits(
    const float* __restrict__ xl, const float* __restrict__ xr,
    const float* __restrict__ We, const float* __restrict__ att,
    const int* __restrict__ src, const int* __restrict__ dstA,
    const float* __restrict__ ea, const float* __restrict__ easum,
    const int* __restrict__ deg, float* __restrict__ logits,
    unsigned* __restrict__ mseg) {
    int lane = threadIdx.x & 63;
    int wave = (blockIdx.x * 256 + threadIdx.x) >> 6;
    int nwaves = (gridDim.x * 256) >> 6;
    int ch0 = lane * 8;
    int head = lane >> 4;
    float wr[4][8], ar[8];
#pragma unroll
    for (int f = 0; f < 4; ++f)
#pragma unroll
        for (int k = 0; k < 8; ++k) wr[f][k] = We[f * HC + ch0 + k];
#pragma unroll
    for (int k = 0; k < 8; ++k) ar[k] = att[ch0 + k];

    for (int idx = wave; idx < Ee + Nn; idx += nwaves) {
        int s, d;
        float eaf[4];
        if (idx < Ee) {
            s = src[idx];
            d = dstA[idx];
            float4 v = ((const float4*)ea)[idx];
            eaf[0] = v.x; eaf[1] = v.y; eaf[2] = v.z; eaf[3] = v.w;
        } else {
            int n = idx - Ee;
            s = n; d = n;
            float dv = (float)max(deg[n], 1);
            float4 v = ((const float4*)easum)[n];
            eaf[0] = v.x / dv; eaf[1] = v.y / dv; eaf[2] = v.z / dv; eaf[3] = v.w / dv;
        }
        const float4* pl = (const float4*)(xl + (size_t)s * HC + ch0);
        const float4* pr = (const float4*)(xr + (size_t)d * HC + ch0);
        float4 l0 = pl[0], l1 = pl[1];
        float4 r0 = pr[0], r1 = pr[1];
        float xa[8] = {l0.x, l0.y, l0.z, l0.w, l1.x, l1.y, l1.z, l1.w};
        float xb[8] = {r0.x, r0.y, r0.z, r0.w, r1.x, r1.y, r1.z, r1.w};
        float p = 0.f;
#pragma unroll
        for (int k = 0; k < 8; ++k) {
            float v = xa[k] + xb[k] + eaf[0] * wr[0][k] + eaf[1] * wr[1][k] +
                      eaf[2] * wr[2][k] + eaf[3] * wr[3][k];
            v = (v > 0.f) ? v : SLOPE * v;
            p += v * ar[k];
        }
#pragma unroll
        for (int off = 8; off; off >>= 1) p += __shfl_xor(p, off);
        if ((lane & 15) == 0) {
            logits[(size_t)idx * 4 + head] = p;
            atomicMax(&mseg[d * 4 + head], encf(p));
        }
    }
}

// ---------- exp(logit - segmax) and segment denom ----------
__global__ void k_expdenom(const int* __restrict__ dstA, float* __restrict__ logits,
                           const unsigned* __restrict__ mseg, float* __restrict__ denom) {
    int idx = blockIdx.x * 256 + threadIdx.x;
    if (idx >= Ee + Nn) return;
    int d = (idx < Ee) ? dstA[idx] : (idx - Ee);
    float4 lg = ((const float4*)logits)[idx];
    float e0 = expf(lg.x - decf(mseg[d * 4 + 0]));
    float e1 = expf(lg.y - decf(mseg[d * 4 + 1]));
    float e2 = expf(lg.z - decf(mseg[d * 4 + 2]));
    float e3 = expf(lg.w - decf(mseg[d * 4 + 3]));
    ((float4*)logits)[idx] = make_float4(e0, e1, e2, e3);
    atomicAdd(&denom[d * 4 + 0], e0);
    atomicAdd(&denom[d * 4 + 1], e1);
    atomicAdd(&denom[d * 4 + 2], e2);
    atomicAdd(&denom[d * 4 + 3], e3);
}

// ---------- per-node gather aggregate + bias + BN + ReLU ----------
// houtf: fp32 output (layer 2, feeds pooling); houtb: bf16 output (layer 1,
// feeds the MFMA GEMM). Exactly one is non-null.
__global__ __launch_bounds__(256) void k_aggregate(
    const float* __restrict__ xl, const float* __restrict__ logits,
    const float* __restrict__ denom, const int* __restrict__ rowptr,
    const int* __restrict__ csr, const int* __restrict__ src,
    const float* __restrict__ bias, const float* __restrict__ gamma,
    const float* __restrict__ beta, const float* __restrict__ mean,
    const float* __restrict__ var, float* __restrict__ houtf,
    __hip_bfloat16* __restrict__ houtb) {
    __shared__ int s_src[64];
    __shared__ float s_ex[64][4];
    int n = blockIdx.x;
    int t = threadIdx.x;
    int c0 = t, c1 = t + 256;
    int h0 = c0 >> 7, h1 = h0 + 2;
    float inv0 = 1.f / denom[n * 4 + h0];
    float inv1 = 1.f / denom[n * 4 + h1];
    float acc0 = 0.f, acc1 = 0.f;
    int start = rowptr[n], end = rowptr[n + 1];
    for (int j0 = start; j0 < end; j0 += 64) {
        int m = min(64, end - j0);
        __syncthreads();
        if (t < m) {
            int eid = csr[j0 + t];
            s_src[t] = src[eid];
            float4 exv = ((const float4*)logits)[eid];
            s_ex[t][0] = exv.x; s_ex[t][1] = exv.y; s_ex[t][2] = exv.z; s_ex[t][3] = exv.w;
        }
        __syncthreads();
        for (int i = 0; i < m; ++i) {
            int s = s_src[i];
            acc0 += s_ex[i][h0] * inv0 * xl[(size_t)s * HC + c0];
            acc1 += s_ex[i][h1] * inv1 * xl[(size_t)s * HC + c1];
        }
    }
    {
        float4 exv = ((const float4*)logits)[Ee + n];
        float seh0 = (h0 == 0) ? exv.x : exv.y;
        float seh1 = (h0 == 0) ? exv.z : exv.w;
        acc0 += seh0 * inv0 * xl[(size_t)n * HC + c0];
        acc1 += seh1 * inv1 * xl[(size_t)n * HC + c1];
    }
    float v0 = acc0 + bias[c0];
    v0 = fmaxf((v0 - mean[c0]) * rsqrtf(var[c0] + EPSf) * gamma[c0] + beta[c0], 0.f);
    float v1 = acc1 + bias[c1];
    v1 = fmaxf((v1 - mean[c1]) * rsqrtf(var[c1] + EPSf) * gamma[c1] + beta[c1], 0.f);
    if (houtf) {
        houtf[(size_t)n * HC + c0] = v0;
        houtf[(size_t)n * HC + c1] = v1;
    }
    if (houtb) {
        houtb[(size_t)n * HC + c0] = __float2bfloat16(v0);
        houtb[(size_t)n * HC + c1] = __float2bfloat16(v1);
    }
}

// ---------- graph size counts ----------
__global__ void k_cnt(const int* __restrict__ batch, float* __restrict__ cnt) {
    int i = blockIdx.x * 256 + threadIdx.x;
    if (i < Nn) atomicAdd(&cnt[batch[i]], 1.f);
}

// ---------- mean-pool accumulate ----------
__global__ void k_pool(const float* __restrict__ h, const int* __restrict__ batch,
                       float* __restrict__ pooled) {
    int idx = blockIdx.x * 256 + threadIdx.x;
    if (idx >= Nn * HC) return;
    int n = idx >> 9, c = idx & 511;
    atomicAdd(&pooled[(size_t)batch[n] * HC + c], h[idx]);
}

// ---------- final MLP ----------
__global__ __launch_bounds__(128) void k_mlp(const float* __restrict__ pooled,
                                             const float* __restrict__ cnt,
                                             const float* __restrict__ gfeat,
                                             const float* __restrict__ fc1w,
                                             const float* __restrict__ fc1b,
                                             const float* __restrict__ fc2w,
                                             const float* __restrict__ fc2b,
                                             float* __restrict__ out) {
    __shared__ float z[HC + GFt];
    __shared__ float red[128];
    int g = blockIdx.x, t = threadIdx.x;
    float ic = 1.f / fmaxf(cnt[g], 1.f);
    for (int i = t; i < HC; i += 128) z[i] = pooled[(size_t)g * HC + i] * ic;
    for (int i = HC + t; i < HC + GFt; i += 128) z[i] = gfeat[g * GFt + (i - HC)];
    __syncthreads();
    float acc = fc1b[t];
    for (int j = 0; j < HC + GFt; ++j) acc += z[j] * fc1w[j * 128 + t];
    float r = fmaxf(acc, 0.f) * fc2w[t];
    red[t] = r;
    __syncthreads();
    for (int off = 64; off; off >>= 1) {
        if (t < off) red[t] += red[t + off];
        __syncthreads();
    }
    if (t == 0) out[g] = red[0] + fc2b[0];
}

extern "C" void kernel_launch(void* const* d_in, const int* in_sizes, int n_in,
                              void* d_out, int out_size, void* d_ws, size_t ws_size,
                              hipStream_t stream) {
    const float* x = (const float*)d_in[0];
    const float* ea = (const float*)d_in[1];
    const float* gfeat = (const float*)d_in[2];
    const float* Wl1 = (const float*)d_in[3];
    const float* Wr1 = (const float*)d_in[4];
    const float* We1 = (const float*)d_in[5];
    const float* att1 = (const float*)d_in[6];
    const float* b1 = (const float*)d_in[7];
    const float* gamma1 = (const float*)d_in[8];
    const float* beta1 = (const float*)d_in[9];
    const float* mean1 = (const float*)d_in[10];
    const float* var1 = (const float*)d_in[11];
    const float* Wl2 = (const float*)d_in[12];
    const float* Wr2 = (const float*)d_in[13];
    const float* We2 = (const float*)d_in[14];
    const float* att2 = (const float*)d_in[15];
    const float* b2 = (const float*)d_in[16];
    const float* gamma2 = (const float*)d_in[17];
    const float* beta2 = (const float*)d_in[18];
    const float* mean2 = (const float*)d_in[19];
    const float* var2 = (const float*)d_in[20];
    const float* fc1w = (const float*)d_in[21];
    const float* fc1b = (const float*)d_in[22];
    const float* fc2w = (const float*)d_in[23];
    const float* fc2b = (const float*)d_in[24];
    const int* eidx = (const int*)d_in[25];
    const int* batch = (const int*)d_in[26];
    float* out = (float*)d_out;

    const int* srcp = eidx;
    const int* dstp = eidx + Ee;

    char* p = (char*)d_ws;
    auto alloc = [&](size_t bytes) -> char* {
        char* r = p;
        p += (bytes + 255) & ~(size_t)255;
        return r;
    };
    float* xl = (float*)alloc((size_t)Nn * HC * 4);
    float* xr = (float*)alloc((size_t)Nn * HC * 4);
    float* h = (float*)alloc((size_t)Nn * HC * 4);  // fp32 h2; low half doubles as bf16 h1
    __hip_bfloat16* h_bf = (__hip_bfloat16*)h;
    float* logits = (float*)alloc((size_t)(Ee + Nn) * 4 * 4);
    float* denom = (float*)alloc((size_t)Nn * 4 * 4);
    unsigned* mseg = (unsigned*)alloc((size_t)Nn * 4 * 4);
    float* easum = (float*)alloc((size_t)Nn * 4 * 4);
    int* deg = (int*)alloc((size_t)Nn * 4);
    int* fill = (int*)alloc((size_t)Nn * 4);
    int* rowptr = (int*)alloc((size_t)(Nn + 1) * 4);
    int* csr = (int*)alloc((size_t)Ee * 4);
    float* pooled = (float*)alloc((size_t)Gg * HC * 4);
    float* cnt = (float*)alloc((size_t)Gg * 4);
    __hip_bfloat16* Wt = (__hip_bfloat16*)alloc((size_t)1024 * 512 * 2);

    hipMemsetAsync(deg, 0, (size_t)Nn * 4, stream);
    hipMemsetAsync(fill, 0, (size_t)Nn * 4, stream);
    hipMemsetAsync(easum, 0, (size_t)Nn * 4 * 4, stream);
    hipMemsetAsync(mseg, 0, (size_t)Nn * 4 * 4, stream);
    hipMemsetAsync(denom, 0, (size_t)Nn * 4 * 4, stream);
    hipMemsetAsync(pooled, 0, (size_t)Gg * HC * 4, stream);
    hipMemsetAsync(cnt, 0, (size_t)Gg * 4, stream);

    k_deg<<<(Ee + 255) / 256, 256, 0, stream>>>(dstp, ea, deg, easum);
    k_scan<<<1, 1024, 0, stream>>>(deg, rowptr);
    k_scatter<<<(Ee + 255) / 256, 256, 0, stream>>>(dstp, rowptr, fill, csr);
    k_cvtW<<<(1024 * 512 + 255) / 256, 256, 0, stream>>>(Wl2, Wr2, Wt);

    // ----- layer 1 -----
    k_xlxr1<<<(Nn * HC + 255) / 256, 256, 0, stream>>>(x, Wl1, Wr1, xl, xr);
    k_logits<<<4096, 256, 0, stream>>>(xl, xr, We1, att1, srcp, dstp, ea, easum, deg,
                                       logits, mseg);
    k_expdenom<<<(Ee + Nn + 255) / 256, 256, 0, stream>>>(dstp, logits, mseg, denom);
    k_aggregate<<<Nn, 256, 0, stream>>>(xl, logits, denom, rowptr, csr, srcp, b1,
                                        gamma1, beta1, mean1, var1, nullptr, h_bf);

    // ----- layer 2 -----
    hipMemsetAsync(mseg, 0, (size_t)Nn * 4 * 4, stream);
    hipMemsetAsync(denom, 0, (size_t)Nn * 4 * 4, stream);
    k_gemm_mfma<<<dim3((Nn + 127) / 128, 8), 256, 0, stream>>>(
        (const short*)h_bf, (const short*)Wt, xl, xr, Nn);
    k_logits<<<4096, 256, 0, stream>>>(xl, xr, We2, att2, srcp, dstp, ea, easum, deg,
                                       logits, mseg);
    k_expdenom<<<(Ee + Nn + 255) / 256, 256, 0, stream>>>(dstp, logits, mseg, denom);
    k_aggregate<<<Nn, 256, 0, stream>>>(xl, logits, denom, rowptr, csr, srcp, b2,
                                        gamma2, beta2, mean2, var2, h, nullptr);

    // ----- pooling + MLP -----
    k_cnt<<<(Nn + 255) / 256, 256, 0, stream>>>(batch, cnt);
    k_pool<<<(Nn * HC + 255) / 256, 256, 0, stream>>>(h, batch, pooled);
    k_mlp<<<Gg, 128, 0, stream>>>(pooled, cnt, gfeat, fc1w, fc1b, fc2w, fc2b, out);
}

// Round 3
// 672.593 us; speedup vs baseline: 2.1876x; 1.5844x over previous
//
#include <hip/hip_runtime.h>
#include <hip/hip_bf16.h>

#define Nn 20000
#define Ee 320000
#define Hh 4
#define Cc 128
#define HC 512
#define Gg 1024
#define NFt 9
#define EFt 4
#define GFt 50
#define EPSf 1e-5f
#define SLOPE 0.2f

typedef __attribute__((ext_vector_type(8))) short bf16x8;
typedef __attribute__((ext_vector_type(4))) float f32x4;

typedef const __attribute__((address_space(1))) unsigned char* gp1_t;
typedef __attribute__((address_space(3))) unsigned char* lp3_t;
__device__ __forceinline__ void gload16(const void* g, void* l) {
    __builtin_amdgcn_global_load_lds((gp1_t)g, (lp3_t)l, 16, 0, 0);
}

__device__ __forceinline__ float bf2f(short s) {
    return __uint_as_float(((unsigned)(unsigned short)s) << 16);
}

// ---------- degree + edge_attr segment sum (for self-loop mean fill) ----------
__global__ void k_deg(const int* __restrict__ dst, const float* __restrict__ ea,
                      int* __restrict__ deg, float* __restrict__ easum) {
    int e = blockIdx.x * 256 + threadIdx.x;
    if (e >= Ee) return;
    int d = dst[e];
    atomicAdd(&deg[d], 1);
    float4 v = ((const float4*)ea)[e];
    atomicAdd(&easum[d * 4 + 0], v.x);
    atomicAdd(&easum[d * 4 + 1], v.y);
    atomicAdd(&easum[d * 4 + 2], v.z);
    atomicAdd(&easum[d * 4 + 3], v.w);
}

// ---------- one-block exclusive scan of deg -> rowptr ----------
__global__ void k_scan(const int* __restrict__ deg, int* __restrict__ rowptr) {
    __shared__ int sums[1024];
    int t = threadIdx.x;
    const int n = Nn;
    int chunk = (n + 1023) / 1024;
    int start = t * chunk;
    int lim = min(start + chunk, n);
    int s = 0;
    for (int i = start; i < lim; ++i) s += deg[i];
    sums[t] = s;
    __syncthreads();
    for (int off = 1; off < 1024; off <<= 1) {
        int v = (t >= off) ? sums[t - off] : 0;
        __syncthreads();
        sums[t] += v;
        __syncthreads();
    }
    int run = (t == 0) ? 0 : sums[t - 1];
    for (int i = start; i < lim; ++i) { rowptr[i] = run; run += deg[i]; }
    if (t == 1023) rowptr[n] = sums[1023];
}

// ---------- counting-sort scatter: csr[pos] = edge id (grouped by dst) ----------
__global__ void k_scatter(const int* __restrict__ dst, const int* __restrict__ rowptr,
                          int* __restrict__ fill, int* __restrict__ csr) {
    int e = blockIdx.x * 256 + threadIdx.x;
    if (e >= Ee) return;
    int d = dst[e];
    int pos = rowptr[d] + atomicAdd(&fill[d], 1);
    csr[pos] = e;
}

// ---------- layer-1 node transforms (K=9), bf16 out ----------
__global__ void k_xlxr1(const float* __restrict__ x, const float* __restrict__ Wl,
                        const float* __restrict__ Wr, __hip_bfloat16* __restrict__ xl,
                        __hip_bfloat16* __restrict__ xr) {
    int idx = blockIdx.x * 256 + threadIdx.x;  // over Nn*256 (2 channels each)
    if (idx >= Nn * 256) return;
    int n = idx >> 8, c = (idx & 255) * 2;
    float a0 = 0.f, a1 = 0.f, r0 = 0.f, r1 = 0.f;
#pragma unroll
    for (int f = 0; f < NFt; ++f) {
        float xv = x[n * NFt + f];
        a0 += xv * Wl[f * HC + c];
        a1 += xv * Wl[f * HC + c + 1];
        r0 += xv * Wr[f * HC + c];
        r1 += xv * Wr[f * HC + c + 1];
    }
    __hip_bfloat162 av, rv;
    av.x = __float2bfloat16(a0); av.y = __float2bfloat16(a1);
    rv.x = __float2bfloat16(r0); rv.y = __float2bfloat16(r1);
    ((__hip_bfloat162*)xl)[idx] = av;
    ((__hip_bfloat162*)xr)[idx] = rv;
}

// ---------- convert [Wl2|Wr2] -> transposed bf16 Wt[1024][512] ----------
__global__ void k_cvtW(const float* __restrict__ Wl2, const float* __restrict__ Wr2,
                       __hip_bfloat16* __restrict__ Wt) {
    int idx = blockIdx.x * 256 + threadIdx.x;
    if (idx >= 1024 * 512) return;
    int col = idx >> 9, k = idx & 511;
    float v = (col < 512) ? Wl2[k * 512 + col] : Wr2[k * 512 + (col - 512)];
    Wt[idx] = __float2bfloat16(v);
}

// ---------- fused bf16 MFMA GEMM: [xl|xr][M x 1024] = h[M x 512] @ Wt^T ----------
__global__ __launch_bounds__(256) void k_gemm_mfma(const short* __restrict__ Abf,
                                                   const short* __restrict__ Bt,
                                                   __hip_bfloat16* __restrict__ xl,
                                                   __hip_bfloat16* __restrict__ xr, int M) {
    __shared__ short As[128 * 32];
    __shared__ short Bs[128 * 32];
    int tid = threadIdx.x;
    int l = tid & 63;
    int wid = tid >> 6;
    int bm0 = blockIdx.x * 128;
    int bn0 = blockIdx.y * 128;
    int wr = (wid >> 1) * 64;
    int wc = (wid & 1) * 64;
    f32x4 acc[4][4] = {};

    int srow = l >> 2;
    int skoff = ((l & 3) ^ ((l >> 3) & 3)) * 8;  // swizzled source granule
    int rk = (((l >> 4) ^ (l >> 1)) & 3) * 8;    // swizzled read granule

    for (int k0 = 0; k0 < 512; k0 += 32) {
        {
            int c = wid;
            long row = min(bm0 + c * 16 + srow, M - 1);
            gload16(Abf + row * 512 + k0 + skoff, &As[c * 512]);
            int col = bn0 + c * 16 + srow;
            gload16(Bt + (size_t)col * 512 + k0 + skoff, &Bs[c * 512]);
            c = wid + 4;
            row = min(bm0 + c * 16 + srow, M - 1);
            gload16(Abf + row * 512 + k0 + skoff, &As[c * 512]);
            col = bn0 + c * 16 + srow;
            gload16(Bt + (size_t)col * 512 + k0 + skoff, &Bs[c * 512]);
        }
        asm volatile("s_waitcnt vmcnt(0)" ::: "memory");
        __syncthreads();
        bf16x8 af[4], bfr[4];
#pragma unroll
        for (int m = 0; m < 4; ++m)
            af[m] = *(const bf16x8*)&As[(wr + m * 16 + (l & 15)) * 32 + rk];
#pragma unroll
        for (int n = 0; n < 4; ++n)
            bfr[n] = *(const bf16x8*)&Bs[(wc + n * 16 + (l & 15)) * 32 + rk];
#pragma unroll
        for (int m = 0; m < 4; ++m)
#pragma unroll
            for (int n = 0; n < 4; ++n)
                acc[m][n] = __builtin_amdgcn_mfma_f32_16x16x32_bf16(af[m], bfr[n],
                                                                    acc[m][n], 0, 0, 0);
        __syncthreads();
    }
    __hip_bfloat16* dst = (bn0 < 512) ? xl : xr;
    int cb = bn0 & 511;
#pragma unroll
    for (int m = 0; m < 4; ++m) {
#pragma unroll
        for (int n = 0; n < 4; ++n) {
            int col = cb + wc + n * 16 + (l & 15);
#pragma unroll
            for (int r = 0; r < 4; ++r) {
                int row = bm0 + wr + m * 16 + (l >> 4) * 4 + r;
                if (row < M) dst[(size_t)row * 512 + col] = __float2bfloat16(acc[m][n][r]);
            }
        }
    }
}

// ---------- fused per-node attention: logits + online softmax + aggregate + BN ----------
// One block per dst node; 4 waves stride the node's (edges + self-loop).
// Wave-local online softmax (m, den, acc[8]/lane); LDS merge at the end.
__global__ __launch_bounds__(256) void k_fused_attn(
    const __hip_bfloat16* __restrict__ xl, const __hip_bfloat16* __restrict__ xr,
    const float* __restrict__ We, const float* __restrict__ att,
    const int* __restrict__ rowptr, const int* __restrict__ csr,
    const int* __restrict__ src, const float* __restrict__ ea,
    const float* __restrict__ easum, const int* __restrict__ deg,
    const float* __restrict__ bias, const float* __restrict__ gamma,
    const float* __restrict__ beta, const float* __restrict__ mean,
    const float* __restrict__ var, float* __restrict__ houtf,
    __hip_bfloat16* __restrict__ houtb) {
    __shared__ float s_acc[4][HC];
    __shared__ float s_m[4][4];
    __shared__ float s_den[4][4];
    int n = blockIdx.x;
    int t = threadIdx.x;
    int l = t & 63;
    int w = t >> 6;
    int ch0 = l * 8;  // lane's 8 channels, all within head l>>4

    float wee[4][8], ar[8], rr[8];
#pragma unroll
    for (int f = 0; f < 4; ++f)
#pragma unroll
        for (int k = 0; k < 8; ++k) wee[f][k] = We[f * HC + ch0 + k];
#pragma unroll
    for (int k = 0; k < 8; ++k) ar[k] = att[ch0 + k];
    {
        bf16x8 rv = *(const bf16x8*)(xr + (size_t)n * HC + ch0);
#pragma unroll
        for (int k = 0; k < 8; ++k) rr[k] = bf2f(rv[k]);
    }

    int start = rowptr[n], end = rowptr[n + 1];  // j==end means self-loop
    float m = -1e30f, den = 0.f;
    float acc[8] = {};

    int j = start + w;
    int s_cur = n;
    float ea_cur[4] = {};
    bf16x8 xl_cur = {};
    if (j <= end) {
        if (j < end) {
            int eid = csr[j];
            s_cur = src[eid];
            float4 v = ((const float4*)ea)[eid];
            ea_cur[0] = v.x; ea_cur[1] = v.y; ea_cur[2] = v.z; ea_cur[3] = v.w;
        } else {
            float dv = (float)max(deg[n], 1);
            float4 v = ((const float4*)easum)[n];
            ea_cur[0] = v.x / dv; ea_cur[1] = v.y / dv; ea_cur[2] = v.z / dv; ea_cur[3] = v.w / dv;
        }
        xl_cur = *(const bf16x8*)(xl + (size_t)s_cur * HC + ch0);
    }
    while (j <= end) {
        int jn = j + 4;
        int s_nxt = n;
        float ea_nxt[4] = {};
        bf16x8 xl_nxt = {};
        if (jn <= end) {  // prefetch next item
            if (jn < end) {
                int eid = csr[jn];
                s_nxt = src[eid];
                float4 v = ((const float4*)ea)[eid];
                ea_nxt[0] = v.x; ea_nxt[1] = v.y; ea_nxt[2] = v.z; ea_nxt[3] = v.w;
            } else {
                float dv = (float)max(deg[n], 1);
                float4 v = ((const float4*)easum)[n];
                ea_nxt[0] = v.x / dv; ea_nxt[1] = v.y / dv; ea_nxt[2] = v.z / dv; ea_nxt[3] = v.w / dv;
            }
            xl_nxt = *(const bf16x8*)(xl + (size_t)s_nxt * HC + ch0);
        }
        // ---- compute current item ----
        float xlv[8];
#pragma unroll
        for (int k = 0; k < 8; ++k) xlv[k] = bf2f(xl_cur[k]);
        float p = 0.f;
#pragma unroll
        for (int k = 0; k < 8; ++k) {
            float v = xlv[k] + rr[k] + ea_cur[0] * wee[0][k] + ea_cur[1] * wee[1][k] +
                      ea_cur[2] * wee[2][k] + ea_cur[3] * wee[3][k];
            v = (v > 0.f) ? v : SLOPE * v;
            p += v * ar[k];
        }
#pragma unroll
        for (int off = 8; off; off >>= 1) p += __shfl_xor(p, off);  // 16-lane head reduce
        float mn = fmaxf(m, p);
        float scale = __expf(m - mn);  // 0 on first item (m=-1e30), 1 if max unchanged
        float ex = __expf(p - mn);
        den = den * scale + ex;
#pragma unroll
        for (int k = 0; k < 8; ++k) acc[k] = acc[k] * scale + ex * xlv[k];
        m = mn;
        // ---- rotate prefetch ----
        j = jn;
        s_cur = s_nxt;
        xl_cur = xl_nxt;
#pragma unroll
        for (int k = 0; k < 4; ++k) ea_cur[k] = ea_nxt[k];
    }

    // ---- merge 4 waves via LDS ----
    *(f32x4*)&s_acc[w][ch0] = *(f32x4*)&acc[0];
    *(f32x4*)&s_acc[w][ch0 + 4] = *(f32x4*)&acc[4];
    if ((l & 15) == 0) {
        s_m[w][l >> 4] = m;
        s_den[w][l >> 4] = den;
    }
    __syncthreads();
#pragma unroll
    for (int half = 0; half < 2; ++half) {
        int c = t + half * 256;
        int hh = c >> 7;
        float M = fmaxf(fmaxf(s_m[0][hh], s_m[1][hh]), fmaxf(s_m[2][hh], s_m[3][hh]));
        float D = 0.f, A = 0.f;
#pragma unroll
        for (int w2 = 0; w2 < 4; ++w2) {
            float sc = __expf(s_m[w2][hh] - M);
            D += s_den[w2][hh] * sc;
            A += s_acc[w2][c] * sc;
        }
        float v = A / D + bias[c];
        v = fmaxf((v - mean[c]) * rsqrtf(var[c] + EPSf) * gamma[c] + beta[c], 0.f);
        if (houtf) houtf[(size_t)n * HC + c] = v;
        else houtb[(size_t)n * HC + c] = __float2bfloat16(v);
    }
}

// ---------- graph size counts ----------
__global__ void k_cnt(const int* __restrict__ batch, float* __restrict__ cnt) {
    int i = blockIdx.x * 256 + threadIdx.x;
    if (i < Nn) atomicAdd(&cnt[batch[i]], 1.f);
}

// ---------- mean-pool accumulate ----------
__global__ void k_pool(const float* __restrict__ h, const int* __restrict__ batch,
                       float* __restrict__ pooled) {
    int idx = blockIdx.x * 256 + threadIdx.x;
    if (idx >= Nn * HC) return;
    int n = idx >> 9, c = idx & 511;
    atomicAdd(&pooled[(size_t)batch[n] * HC + c], h[idx]);
}

// ---------- final MLP ----------
__global__ __launch_bounds__(128) void k_mlp(const float* __restrict__ pooled,
                                             const float* __restrict__ cnt,
                                             const float* __restrict__ gfeat,
                                             const float* __restrict__ fc1w,
                                             const float* __restrict__ fc1b,
                                             const float* __restrict__ fc2w,
                                             const float* __restrict__ fc2b,
                                             float* __restrict__ out) {
    __shared__ float z[HC + GFt];
    __shared__ float red[128];
    int g = blockIdx.x, t = threadIdx.x;
    float ic = 1.f / fmaxf(cnt[g], 1.f);
    for (int i = t; i < HC; i += 128) z[i] = pooled[(size_t)g * HC + i] * ic;
    for (int i = HC + t; i < HC + GFt; i += 128) z[i] = gfeat[g * GFt + (i - HC)];
    __syncthreads();
    float acc = fc1b[t];
    for (int j = 0; j < HC + GFt; ++j) acc += z[j] * fc1w[j * 128 + t];
    float r = fmaxf(acc, 0.f) * fc2w[t];
    red[t] = r;
    __syncthreads();
    for (int off = 64; off; off >>= 1) {
        if (t < off) red[t] += red[t + off];
        __syncthreads();
    }
    if (t == 0) out[g] = red[0] + fc2b[0];
}

extern "C" void kernel_launch(void* const* d_in, const int* in_sizes, int n_in,
                              void* d_out, int out_size, void* d_ws, size_t ws_size,
                              hipStream_t stream) {
    const float* x = (const float*)d_in[0];
    const float* ea = (const float*)d_in[1];
    const float* gfeat = (const float*)d_in[2];
    const float* Wl1 = (const float*)d_in[3];
    const float* Wr1 = (const float*)d_in[4];
    const float* We1 = (const float*)d_in[5];
    const float* att1 = (const float*)d_in[6];
    const float* b1 = (const float*)d_in[7];
    const float* gamma1 = (const float*)d_in[8];
    const float* beta1 = (const float*)d_in[9];
    const float* mean1 = (const float*)d_in[10];
    const float* var1 = (const float*)d_in[11];
    const float* Wl2 = (const float*)d_in[12];
    const float* Wr2 = (const float*)d_in[13];
    const float* We2 = (const float*)d_in[14];
    const float* att2 = (const float*)d_in[15];
    const float* b2 = (const float*)d_in[16];
    const float* gamma2 = (const float*)d_in[17];
    const float* beta2 = (const float*)d_in[18];
    const float* mean2 = (const float*)d_in[19];
    const float* var2 = (const float*)d_in[20];
    const float* fc1w = (const float*)d_in[21];
    const float* fc1b = (const float*)d_in[22];
    const float* fc2w = (const float*)d_in[23];
    const float* fc2b = (const float*)d_in[24];
    const int* eidx = (const int*)d_in[25];
    const int* batch = (const int*)d_in[26];
    float* out = (float*)d_out;

    const int* srcp = eidx;
    const int* dstp = eidx + Ee;

    char* p = (char*)d_ws;
    auto alloc = [&](size_t bytes) -> char* {
        char* r = p;
        p += (bytes + 255) & ~(size_t)255;
        return r;
    };
    __hip_bfloat16* xl = (__hip_bfloat16*)alloc((size_t)Nn * HC * 2);
    __hip_bfloat16* xr = (__hip_bfloat16*)alloc((size_t)Nn * HC * 2);
    float* h = (float*)alloc((size_t)Nn * HC * 4);  // fp32 h2; low half doubles as bf16 h1
    __hip_bfloat16* h_bf = (__hip_bfloat16*)h;
    float* easum = (float*)alloc((size_t)Nn * 4 * 4);
    int* deg = (int*)alloc((size_t)Nn * 4);
    int* fill = (int*)alloc((size_t)Nn * 4);
    int* rowptr = (int*)alloc((size_t)(Nn + 1) * 4);
    int* csr = (int*)alloc((size_t)Ee * 4);
    float* pooled = (float*)alloc((size_t)Gg * HC * 4);
    float* cnt = (float*)alloc((size_t)Gg * 4);
    __hip_bfloat16* Wt = (__hip_bfloat16*)alloc((size_t)1024 * 512 * 2);

    hipMemsetAsync(deg, 0, (size_t)Nn * 4, stream);
    hipMemsetAsync(fill, 0, (size_t)Nn * 4, stream);
    hipMemsetAsync(easum, 0, (size_t)Nn * 4 * 4, stream);
    hipMemsetAsync(pooled, 0, (size_t)Gg * HC * 4, stream);
    hipMemsetAsync(cnt, 0, (size_t)Gg * 4, stream);

    k_deg<<<(Ee + 255) / 256, 256, 0, stream>>>(dstp, ea, deg, easum);
    k_scan<<<1, 1024, 0, stream>>>(deg, rowptr);
    k_scatter<<<(Ee + 255) / 256, 256, 0, stream>>>(dstp, rowptr, fill, csr);
    k_cvtW<<<(1024 * 512 + 255) / 256, 256, 0, stream>>>(Wl2, Wr2, Wt);

    // ----- layer 1 -----
    k_xlxr1<<<(Nn * 256 + 255) / 256, 256, 0, stream>>>(x, Wl1, Wr1, xl, xr);
    k_fused_attn<<<Nn, 256, 0, stream>>>(xl, xr, We1, att1, rowptr, csr, srcp, ea,
                                         easum, deg, b1, gamma1, beta1, mean1, var1,
                                         nullptr, h_bf);

    // ----- layer 2 -----
    k_gemm_mfma<<<dim3((Nn + 127) / 128, 8), 256, 0, stream>>>(
        (const short*)h_bf, (const short*)Wt, xl, xr, Nn);
    k_fused_attn<<<Nn, 256, 0, stream>>>(xl, xr, We2, att2, rowptr, csr, srcp, ea,
                                         easum, deg, b2, gamma2, beta2, mean2, var2,
                                         h, nullptr);

    // ----- pooling + MLP -----
    k_cnt<<<(Nn + 255) / 256, 256, 0, stream>>>(batch, cnt);
    k_pool<<<(Nn * HC + 255) / 256, 256, 0, stream>>>(h, batch, pooled);
    k_mlp<<<Gg, 128, 0, stream>>>(pooled, cnt, gfeat, fc1w, fc1b, fc2w, fc2b, out);
}

// Round 4
// 600.920 us; speedup vs baseline: 2.4485x; 1.1193x over previous
//
#include <hip/hip_runtime.h>
#include <hip/hip_bf16.h>

#define Nn 20000
#define Ee 320000
#define Hh 4
#define Cc 128
#define HC 512
#define Gg 1024
#define NFt 9
#define EFt 4
#define GFt 50
#define EPSf 1e-5f
#define SLOPE 0.2f

typedef __attribute__((ext_vector_type(8))) short bf16x8;
typedef __attribute__((ext_vector_type(4))) float f32x4;

typedef const __attribute__((address_space(1))) unsigned char* gp1_t;
typedef __attribute__((address_space(3))) unsigned char* lp3_t;
__device__ __forceinline__ void gload16(const void* g, void* l) {
    __builtin_amdgcn_global_load_lds((gp1_t)g, (lp3_t)l, 16, 0, 0);
}

__device__ __forceinline__ float bf2f(short s) {
    return __uint_as_float(((unsigned)(unsigned short)s) << 16);
}

// ---------- degree + edge_attr segment sum (for self-loop mean fill) ----------
__global__ void k_deg(const int* __restrict__ dst, const float* __restrict__ ea,
                      int* __restrict__ deg, float* __restrict__ easum) {
    int e = blockIdx.x * 256 + threadIdx.x;
    if (e >= Ee) return;
    int d = dst[e];
    atomicAdd(&deg[d], 1);
    float4 v = ((const float4*)ea)[e];
    atomicAdd(&easum[d * 4 + 0], v.x);
    atomicAdd(&easum[d * 4 + 1], v.y);
    atomicAdd(&easum[d * 4 + 2], v.z);
    atomicAdd(&easum[d * 4 + 3], v.w);
}

// ---------- one-block exclusive scan of deg -> rowptr ----------
__global__ void k_scan(const int* __restrict__ deg, int* __restrict__ rowptr) {
    __shared__ int sums[1024];
    int t = threadIdx.x;
    const int n = Nn;
    int chunk = (n + 1023) / 1024;
    int start = t * chunk;
    int lim = min(start + chunk, n);
    int s = 0;
    for (int i = start; i < lim; ++i) s += deg[i];
    sums[t] = s;
    __syncthreads();
    for (int off = 1; off < 1024; off <<= 1) {
        int v = (t >= off) ? sums[t - off] : 0;
        __syncthreads();
        sums[t] += v;
        __syncthreads();
    }
    int run = (t == 0) ? 0 : sums[t - 1];
    for (int i = start; i < lim; ++i) { rowptr[i] = run; run += deg[i]; }
    if (t == 1023) rowptr[n] = sums[1023];
}

// ---------- counting-sort scatter: store src id + edge_attr in CSR order ----------
__global__ void k_scatter(const int* __restrict__ src, const int* __restrict__ dst,
                          const float* __restrict__ ea, const int* __restrict__ rowptr,
                          int* __restrict__ fill, int* __restrict__ csr_src,
                          float4* __restrict__ ea_s) {
    int e = blockIdx.x * 256 + threadIdx.x;
    if (e >= Ee) return;
    int d = dst[e];
    int pos = rowptr[d] + atomicAdd(&fill[d], 1);
    csr_src[pos] = src[e];
    ea_s[pos] = ((const float4*)ea)[e];
}

// ---------- layer-1 node transforms (K=9), bf16 out ----------
__global__ void k_xlxr1(const float* __restrict__ x, const float* __restrict__ Wl,
                        const float* __restrict__ Wr, __hip_bfloat16* __restrict__ xl,
                        __hip_bfloat16* __restrict__ xr) {
    int idx = blockIdx.x * 256 + threadIdx.x;  // over Nn*256 (2 channels each)
    if (idx >= Nn * 256) return;
    int n = idx >> 8, c = (idx & 255) * 2;
    float a0 = 0.f, a1 = 0.f, r0 = 0.f, r1 = 0.f;
#pragma unroll
    for (int f = 0; f < NFt; ++f) {
        float xv = x[n * NFt + f];
        a0 += xv * Wl[f * HC + c];
        a1 += xv * Wl[f * HC + c + 1];
        r0 += xv * Wr[f * HC + c];
        r1 += xv * Wr[f * HC + c + 1];
    }
    __hip_bfloat162 av, rv;
    av.x = __float2bfloat16(a0); av.y = __float2bfloat16(a1);
    rv.x = __float2bfloat16(r0); rv.y = __float2bfloat16(r1);
    ((__hip_bfloat162*)xl)[idx] = av;
    ((__hip_bfloat162*)xr)[idx] = rv;
}

// ---------- convert [Wl2|Wr2] -> transposed bf16 Wt[1024][512] ----------
__global__ void k_cvtW(const float* __restrict__ Wl2, const float* __restrict__ Wr2,
                       __hip_bfloat16* __restrict__ Wt) {
    int idx = blockIdx.x * 256 + threadIdx.x;
    if (idx >= 1024 * 512) return;
    int col = idx >> 9, k = idx & 511;
    float v = (col < 512) ? Wl2[k * 512 + col] : Wr2[k * 512 + (col - 512)];
    Wt[idx] = __float2bfloat16(v);
}

// ---------- fused bf16 MFMA GEMM: [xl|xr][M x 1024] = h[M x 512] @ Wt^T ----------
__global__ __launch_bounds__(256) void k_gemm_mfma(const short* __restrict__ Abf,
                                                   const short* __restrict__ Bt,
                                                   __hip_bfloat16* __restrict__ xl,
                                                   __hip_bfloat16* __restrict__ xr, int M) {
    __shared__ short As[128 * 32];
    __shared__ short Bs[128 * 32];
    int tid = threadIdx.x;
    int l = tid & 63;
    int wid = tid >> 6;
    int bm0 = blockIdx.x * 128;
    int bn0 = blockIdx.y * 128;
    int wr = (wid >> 1) * 64;
    int wc = (wid & 1) * 64;
    f32x4 acc[4][4] = {};

    int srow = l >> 2;
    int skoff = ((l & 3) ^ ((l >> 3) & 3)) * 8;  // swizzled source granule
    int rk = (((l >> 4) ^ (l >> 1)) & 3) * 8;    // swizzled read granule

    for (int k0 = 0; k0 < 512; k0 += 32) {
        {
            int c = wid;
            long row = min(bm0 + c * 16 + srow, M - 1);
            gload16(Abf + row * 512 + k0 + skoff, &As[c * 512]);
            int col = bn0 + c * 16 + srow;
            gload16(Bt + (size_t)col * 512 + k0 + skoff, &Bs[c * 512]);
            c = wid + 4;
            row = min(bm0 + c * 16 + srow, M - 1);
            gload16(Abf + row * 512 + k0 + skoff, &As[c * 512]);
            col = bn0 + c * 16 + srow;
            gload16(Bt + (size_t)col * 512 + k0 + skoff, &Bs[c * 512]);
        }
        asm volatile("s_waitcnt vmcnt(0)" ::: "memory");
        __syncthreads();
        bf16x8 af[4], bfr[4];
#pragma unroll
        for (int m = 0; m < 4; ++m)
            af[m] = *(const bf16x8*)&As[(wr + m * 16 + (l & 15)) * 32 + rk];
#pragma unroll
        for (int n = 0; n < 4; ++n)
            bfr[n] = *(const bf16x8*)&Bs[(wc + n * 16 + (l & 15)) * 32 + rk];
#pragma unroll
        for (int m = 0; m < 4; ++m)
#pragma unroll
            for (int n = 0; n < 4; ++n)
                acc[m][n] = __builtin_amdgcn_mfma_f32_16x16x32_bf16(af[m], bfr[n],
                                                                    acc[m][n], 0, 0, 0);
        __syncthreads();
    }
    __hip_bfloat16* dst = (bn0 < 512) ? xl : xr;
    int cb = bn0 & 511;
#pragma unroll
    for (int m = 0; m < 4; ++m) {
#pragma unroll
        for (int n = 0; n < 4; ++n) {
            int col = cb + wc + n * 16 + (l & 15);
#pragma unroll
            for (int r = 0; r < 4; ++r) {
                int row = bm0 + wr + m * 16 + (l >> 4) * 4 + r;
                if (row < M) dst[(size_t)row * 512 + col] = __float2bfloat16(acc[m][n][r]);
            }
        }
    }
}

// ---------- fused per-node attention: one WAVE per node, chunk-4 pipeline ----------
__global__ __launch_bounds__(256) void k_fused_attn(
    const __hip_bfloat16* __restrict__ xl, const __hip_bfloat16* __restrict__ xr,
    const float* __restrict__ We, const float* __restrict__ att,
    const int* __restrict__ rowptr, const int* __restrict__ csr_src,
    const float4* __restrict__ ea_s, const float* __restrict__ easum,
    const int* __restrict__ deg, const float* __restrict__ bias,
    const float* __restrict__ gamma, const float* __restrict__ beta,
    const float* __restrict__ mean, const float* __restrict__ var,
    float* __restrict__ houtf, __hip_bfloat16* __restrict__ houtb) {
    int n = blockIdx.x * 4 + (threadIdx.x >> 6);
    if (n >= Nn) return;
    int l = threadIdx.x & 63;
    int ch0 = l * 8;  // 8 channels per lane, all within head l>>4

    float wee[4][8], ar[8], rr[8];
#pragma unroll
    for (int f = 0; f < 4; ++f)
#pragma unroll
        for (int k = 0; k < 8; ++k) wee[f][k] = We[f * HC + ch0 + k];
#pragma unroll
    for (int k = 0; k < 8; ++k) ar[k] = att[ch0 + k];
    {
        bf16x8 rv = *(const bf16x8*)(xr + (size_t)n * HC + ch0);
#pragma unroll
        for (int k = 0; k < 8; ++k) rr[k] = bf2f(rv[k]);
    }

    int start = rowptr[n];
    int total = rowptr[n + 1] - start + 1;  // + self-loop (last item)

    float m = -1e30f, den = 0.f;
    float acc[8] = {};

    // meta loader: item i (clamped to self-loop for i >= total-1, always safe)
    auto meta = [&](int i, int& s, float4& ev) {
        if (i < total - 1) {
            s = csr_src[start + i];
            ev = ea_s[start + i];
        } else {
            s = n;
            float dv = (float)max(deg[n], 1);
            float4 v = ((const float4*)easum)[n];
            ev = make_float4(v.x / dv, v.y / dv, v.z / dv, v.w / dv);
        }
    };

    int s0, s1, s2, s3;
    float4 e0, e1, e2, e3;
    meta(0, s0, e0); meta(1, s1, e1); meta(2, s2, e2); meta(3, s3, e3);

    for (int base = 0; base < total; base += 4) {
        // issue 4 independent gathers
        bf16x8 x0 = *(const bf16x8*)(xl + (size_t)s0 * HC + ch0);
        bf16x8 x1 = *(const bf16x8*)(xl + (size_t)s1 * HC + ch0);
        bf16x8 x2 = *(const bf16x8*)(xl + (size_t)s2 * HC + ch0);
        bf16x8 x3 = *(const bf16x8*)(xl + (size_t)s3 * HC + ch0);
        // prefetch next chunk's meta (sequential loads, overlaps compute)
        int ns0, ns1, ns2, ns3;
        float4 ne0, ne1, ne2, ne3;
        meta(base + 4, ns0, ne0); meta(base + 5, ns1, ne1);
        meta(base + 6, ns2, ne2); meta(base + 7, ns3, ne3);

        // logits for the 4 items
        float p0 = 0.f, p1 = 0.f, p2 = 0.f, p3 = 0.f;
#pragma unroll
        for (int k = 0; k < 8; ++k) {
            float v0 = bf2f(x0[k]) + rr[k] + e0.x * wee[0][k] + e0.y * wee[1][k] +
                       e0.z * wee[2][k] + e0.w * wee[3][k];
            float v1 = bf2f(x1[k]) + rr[k] + e1.x * wee[0][k] + e1.y * wee[1][k] +
                       e1.z * wee[2][k] + e1.w * wee[3][k];
            float v2 = bf2f(x2[k]) + rr[k] + e2.x * wee[0][k] + e2.y * wee[1][k] +
                       e2.z * wee[2][k] + e2.w * wee[3][k];
            float v3 = bf2f(x3[k]) + rr[k] + e3.x * wee[0][k] + e3.y * wee[1][k] +
                       e3.z * wee[2][k] + e3.w * wee[3][k];
            v0 = (v0 > 0.f) ? v0 : SLOPE * v0;
            v1 = (v1 > 0.f) ? v1 : SLOPE * v1;
            v2 = (v2 > 0.f) ? v2 : SLOPE * v2;
            v3 = (v3 > 0.f) ? v3 : SLOPE * v3;
            p0 += v0 * ar[k];
            p1 += v1 * ar[k];
            p2 += v2 * ar[k];
            p3 += v3 * ar[k];
        }
#pragma unroll
        for (int off = 8; off; off >>= 1) {  // 16-lane (per-head) butterfly
            p0 += __shfl_xor(p0, off);
            p1 += __shfl_xor(p1, off);
            p2 += __shfl_xor(p2, off);
            p3 += __shfl_xor(p3, off);
        }
        // mask padded items (wave-uniform branches)
        if (base + 1 >= total) p1 = -1e30f;
        if (base + 2 >= total) p2 = -1e30f;
        if (base + 3 >= total) p3 = -1e30f;

        // single online-softmax rescale per chunk
        float mn = fmaxf(fmaxf(fmaxf(p0, p1), fmaxf(p2, p3)), m);
        float scale = __expf(m - mn);
        float ex0 = __expf(p0 - mn), ex1 = __expf(p1 - mn);
        float ex2 = __expf(p2 - mn), ex3 = __expf(p3 - mn);
        den = den * scale + ex0 + ex1 + ex2 + ex3;
#pragma unroll
        for (int k = 0; k < 8; ++k) {
            acc[k] = acc[k] * scale + ex0 * bf2f(x0[k]) + ex1 * bf2f(x1[k]) +
                     ex2 * bf2f(x2[k]) + ex3 * bf2f(x3[k]);
        }
        m = mn;
        s0 = ns0; s1 = ns1; s2 = ns2; s3 = ns3;
        e0 = ne0; e1 = ne1; e2 = ne2; e3 = ne3;
    }

    float iden = 1.f / den;
    float4 bi0 = *(const float4*)&bias[ch0], bi1 = *(const float4*)&bias[ch0 + 4];
    float4 ga0 = *(const float4*)&gamma[ch0], ga1 = *(const float4*)&gamma[ch0 + 4];
    float4 be0 = *(const float4*)&beta[ch0], be1 = *(const float4*)&beta[ch0 + 4];
    float4 me0 = *(const float4*)&mean[ch0], me1 = *(const float4*)&mean[ch0 + 4];
    float4 va0 = *(const float4*)&var[ch0], va1 = *(const float4*)&var[ch0 + 4];
    float bi[8] = {bi0.x, bi0.y, bi0.z, bi0.w, bi1.x, bi1.y, bi1.z, bi1.w};
    float ga[8] = {ga0.x, ga0.y, ga0.z, ga0.w, ga1.x, ga1.y, ga1.z, ga1.w};
    float be[8] = {be0.x, be0.y, be0.z, be0.w, be1.x, be1.y, be1.z, be1.w};
    float me[8] = {me0.x, me0.y, me0.z, me0.w, me1.x, me1.y, me1.z, me1.w};
    float va[8] = {va0.x, va0.y, va0.z, va0.w, va1.x, va1.y, va1.z, va1.w};
    if (houtf) {
        float o[8];
#pragma unroll
        for (int k = 0; k < 8; ++k) {
            float v = acc[k] * iden + bi[k];
            o[k] = fmaxf((v - me[k]) * rsqrtf(va[k] + EPSf) * ga[k] + be[k], 0.f);
        }
        *(f32x4*)(houtf + (size_t)n * HC + ch0) = *(f32x4*)&o[0];
        *(f32x4*)(houtf + (size_t)n * HC + ch0 + 4) = *(f32x4*)&o[4];
    } else {
        bf16x8 ob;
#pragma unroll
        for (int k = 0; k < 8; ++k) {
            float v = acc[k] * iden + bi[k];
            v = fmaxf((v - me[k]) * rsqrtf(va[k] + EPSf) * ga[k] + be[k], 0.f);
            union { float f; unsigned u; } cv;
            cv.f = v;
            unsigned r = (cv.u + 0x7fff + ((cv.u >> 16) & 1)) >> 16;
            ob[k] = (short)r;
        }
        *(bf16x8*)(houtb + (size_t)n * HC + ch0) = ob;
    }
}

// ---------- graph offsets from sorted batch ----------
__global__ void k_gofs(const int* __restrict__ batch, int* __restrict__ gofs) {
    int i = blockIdx.x * 256 + threadIdx.x;
    if (i >= Nn) return;
    int b = batch[i];
    if (i == 0) {
        for (int g = 0; g <= b; ++g) gofs[g] = 0;
    } else {
        int bp = batch[i - 1];
        for (int g = bp + 1; g <= b; ++g) gofs[g] = i;
    }
    if (i == Nn - 1) {
        for (int g = b + 1; g <= Gg; ++g) gofs[g] = Nn;
    }
}

// ---------- mean-pool over contiguous node range per graph ----------
__global__ __launch_bounds__(256) void k_pool2(const float* __restrict__ h,
                                               const int* __restrict__ gofs,
                                               float* __restrict__ pooled) {
    int g = blockIdx.x;
    int t = threadIdx.x;
    int s = gofs[g], e = gofs[g + 1];
    float a0 = 0.f, a1 = 0.f;
    for (int r = s; r < e; ++r) {
        float2 v = ((const float2*)(h + (size_t)r * HC))[t];
        a0 += v.x;
        a1 += v.y;
    }
    float ic = (e > s) ? 1.f / (float)(e - s) : 0.f;
    float2 o;
    o.x = a0 * ic;
    o.y = a1 * ic;
    ((float2*)(pooled + (size_t)g * HC))[t] = o;
}

// ---------- final MLP (pooled already mean) ----------
__global__ __launch_bounds__(128) void k_mlp(const float* __restrict__ pooled,
                                             const float* __restrict__ gfeat,
                                             const float* __restrict__ fc1w,
                                             const float* __restrict__ fc1b,
                                             const float* __restrict__ fc2w,
                                             const float* __restrict__ fc2b,
                                             float* __restrict__ out) {
    __shared__ float z[HC + GFt];
    __shared__ float red[128];
    int g = blockIdx.x, t = threadIdx.x;
    for (int i = t; i < HC; i += 128) z[i] = pooled[(size_t)g * HC + i];
    for (int i = HC + t; i < HC + GFt; i += 128) z[i] = gfeat[g * GFt + (i - HC)];
    __syncthreads();
    float acc = fc1b[t];
    for (int j = 0; j < HC + GFt; ++j) acc += z[j] * fc1w[j * 128 + t];
    float r = fmaxf(acc, 0.f) * fc2w[t];
    red[t] = r;
    __syncthreads();
    for (int off = 64; off; off >>= 1) {
        if (t < off) red[t] += red[t + off];
        __syncthreads();
    }
    if (t == 0) out[g] = red[0] + fc2b[0];
}

extern "C" void kernel_launch(void* const* d_in, const int* in_sizes, int n_in,
                              void* d_out, int out_size, void* d_ws, size_t ws_size,
                              hipStream_t stream) {
    const float* x = (const float*)d_in[0];
    const float* ea = (const float*)d_in[1];
    const float* gfeat = (const float*)d_in[2];
    const float* Wl1 = (const float*)d_in[3];
    const float* Wr1 = (const float*)d_in[4];
    const float* We1 = (const float*)d_in[5];
    const float* att1 = (const float*)d_in[6];
    const float* b1 = (const float*)d_in[7];
    const float* gamma1 = (const float*)d_in[8];
    const float* beta1 = (const float*)d_in[9];
    const float* mean1 = (const float*)d_in[10];
    const float* var1 = (const float*)d_in[11];
    const float* Wl2 = (const float*)d_in[12];
    const float* Wr2 = (const float*)d_in[13];
    const float* We2 = (const float*)d_in[14];
    const float* att2 = (const float*)d_in[15];
    const float* b2 = (const float*)d_in[16];
    const float* gamma2 = (const float*)d_in[17];
    const float* beta2 = (const float*)d_in[18];
    const float* mean2 = (const float*)d_in[19];
    const float* var2 = (const float*)d_in[20];
    const float* fc1w = (const float*)d_in[21];
    const float* fc1b = (const float*)d_in[22];
    const float* fc2w = (const float*)d_in[23];
    const float* fc2b = (const float*)d_in[24];
    const int* eidx = (const int*)d_in[25];
    const int* batch = (const int*)d_in[26];
    float* out = (float*)d_out;

    const int* srcp = eidx;
    const int* dstp = eidx + Ee;

    char* p = (char*)d_ws;
    auto alloc = [&](size_t bytes) -> char* {
        char* r = p;
        p += (bytes + 255) & ~(size_t)255;
        return r;
    };
    __hip_bfloat16* xl = (__hip_bfloat16*)alloc((size_t)Nn * HC * 2);
    __hip_bfloat16* xr = (__hip_bfloat16*)alloc((size_t)Nn * HC * 2);
    float* h = (float*)alloc((size_t)Nn * HC * 4);  // fp32 h2; low half doubles as bf16 h1
    __hip_bfloat16* h_bf = (__hip_bfloat16*)h;
    float* easum = (float*)alloc((size_t)Nn * 4 * 4);
    int* deg = (int*)alloc((size_t)Nn * 4);
    int* fill = (int*)alloc((size_t)Nn * 4);
    int* rowptr = (int*)alloc((size_t)(Nn + 1) * 4);
    int* csr_src = (int*)alloc((size_t)Ee * 4);
    float4* ea_s = (float4*)alloc((size_t)Ee * 16);
    float* pooled = (float*)alloc((size_t)Gg * HC * 4);
    int* gofs = (int*)alloc((size_t)(Gg + 1) * 4);
    __hip_bfloat16* Wt = (__hip_bfloat16*)alloc((size_t)1024 * 512 * 2);

    hipMemsetAsync(deg, 0, (size_t)Nn * 4, stream);
    hipMemsetAsync(fill, 0, (size_t)Nn * 4, stream);
    hipMemsetAsync(easum, 0, (size_t)Nn * 4 * 4, stream);

    k_deg<<<(Ee + 255) / 256, 256, 0, stream>>>(dstp, ea, deg, easum);
    k_scan<<<1, 1024, 0, stream>>>(deg, rowptr);
    k_scatter<<<(Ee + 255) / 256, 256, 0, stream>>>(srcp, dstp, ea, rowptr, fill,
                                                    csr_src, ea_s);
    k_cvtW<<<(1024 * 512 + 255) / 256, 256, 0, stream>>>(Wl2, Wr2, Wt);
    k_gofs<<<(Nn + 255) / 256, 256, 0, stream>>>(batch, gofs);

    // ----- layer 1 -----
    k_xlxr1<<<(Nn * 256 + 255) / 256, 256, 0, stream>>>(x, Wl1, Wr1, xl, xr);
    k_fused_attn<<<(Nn + 3) / 4, 256, 0, stream>>>(xl, xr, We1, att1, rowptr, csr_src,
                                                   ea_s, easum, deg, b1, gamma1, beta1,
                                                   mean1, var1, nullptr, h_bf);

    // ----- layer 2 -----
    k_gemm_mfma<<<dim3((Nn + 127) / 128, 8), 256, 0, stream>>>(
        (const short*)h_bf, (const short*)Wt, xl, xr, Nn);
    k_fused_attn<<<(Nn + 3) / 4, 256, 0, stream>>>(xl, xr, We2, att2, rowptr, csr_src,
                                                   ea_s, easum, deg, b2, gamma2, beta2,
                                                   mean2, var2, h, nullptr);

    // ----- pooling + MLP -----
    k_pool2<<<Gg, 256, 0, stream>>>(h, gofs, pooled);
    k_mlp<<<Gg, 128, 0, stream>>>(pooled, gfeat, fc1w, fc1b, fc2w, fc2b, out);
}